// Round 1
// baseline (1074.011 us; speedup 1.0000x reference)
//
#include <hip/hip_runtime.h>
#include <hip/hip_bf16.h>
#include <math.h>

// Problem constants (match reference)
// N=100000, E=600000, D=128, H=4, F=32, L=3

// ---------------------------------------------------------------------------
// x init: x[n,d] = weights[n]*lin_W[d] + lin_b[d]
__global__ __launch_bounds__(256) void initx_kernel(
    const float* __restrict__ w, const float* __restrict__ lW,
    const float* __restrict__ lb, float* __restrict__ x, int N)
{
    int i = blockIdx.x * 256 + threadIdx.x;
    if (i >= N * 128) return;
    int n = i >> 7, d = i & 127;
    x[i] = w[n] * lW[d] + lb[d];
}

// ---------------------------------------------------------------------------
// CSR build
__global__ __launch_bounds__(256) void deg_init_kernel(int* __restrict__ deg, int N)
{
    int i = blockIdx.x * 256 + threadIdx.x;
    if (i < N) deg[i] = 1;  // self loop
}

__global__ __launch_bounds__(256) void deg_count_kernel(
    const int* __restrict__ dst, int* __restrict__ deg, int E)
{
    int i = blockIdx.x * 256 + threadIdx.x;
    if (i < E) atomicAdd(&deg[dst[i]], 1);
}

__global__ __launch_bounds__(1024) void scan_kernel(
    const int* __restrict__ deg, int* __restrict__ rowp, int* __restrict__ cur, int N)
{
    __shared__ int part[1024];
    int t = threadIdx.x;
    int chunk = (N + 1023) / 1024;
    int lo = t * chunk;
    int hi = lo + chunk; if (hi > N) hi = N; if (lo > N) lo = N;
    int s = 0;
    for (int i = lo; i < hi; ++i) s += deg[i];
    part[t] = s;
    __syncthreads();
    for (int off = 1; off < 1024; off <<= 1) {
        int v = (t >= off) ? part[t - off] : 0;
        __syncthreads();
        part[t] += v;
        __syncthreads();
    }
    int run = (t == 0) ? 0 : part[t - 1];
    for (int i = lo; i < hi; ++i) { rowp[i] = run; cur[i] = run; run += deg[i]; }
    if (t == 1023) rowp[N] = part[1023];
}

__global__ __launch_bounds__(256) void scatter_kernel(
    const int* __restrict__ src, const int* __restrict__ dst,
    int* __restrict__ cur, int* __restrict__ col, int E, int N)
{
    int i = blockIdx.x * 256 + threadIdx.x;
    if (i < E) {
        int p = atomicAdd(&cur[dst[i]], 1);
        col[p] = src[i];
    } else if (i < E + N) {
        int v = i - E;
        int p = atomicAdd(&cur[v], 1);
        col[p] = v;  // self loop
    }
}

// ---------------------------------------------------------------------------
// GEMM: h[n,j] = sum_d act(x[n,d]) * W[j,d]   (W row-major [128,128])
// BM=64 rows, BN=128 cols (all), BK=32. 256 threads, 8x4 micro-tile.
__global__ __launch_bounds__(256) void gemm_kernel(
    const float* __restrict__ x, const float* __restrict__ W,
    float* __restrict__ h, int N, int leaky)
{
    __shared__ float xs[32][72];    // [d][row], padded
    __shared__ float wsh[32][132];  // [d][j], padded
    const int tid = threadIdx.x;
    const int m0 = blockIdx.x * 64;
    const int tx = tid & 31;   // col group: j = tx*4 .. +3
    const int ty = tid >> 5;   // row group: n = ty*8 .. +7

    float acc[8][4];
#pragma unroll
    for (int r = 0; r < 8; ++r)
#pragma unroll
        for (int c = 0; c < 4; ++c) acc[r][c] = 0.f;

    const int lr = tid >> 3;          // 0..31
    const int lc = (tid & 7) * 4;     // 0,4,...,28

    for (int k0 = 0; k0 < 128; k0 += 32) {
        // stage x tile (64 x 32), transposed into xs[d][row]
#pragma unroll
        for (int p = 0; p < 2; ++p) {
            int row = m0 + lr + p * 32;
            float4 v = make_float4(0.f, 0.f, 0.f, 0.f);
            if (row < N) v = *reinterpret_cast<const float4*>(&x[(size_t)row * 128 + k0 + lc]);
            if (leaky) {
                v.x = v.x >= 0.f ? v.x : 0.01f * v.x;
                v.y = v.y >= 0.f ? v.y : 0.01f * v.y;
                v.z = v.z >= 0.f ? v.z : 0.01f * v.z;
                v.w = v.w >= 0.f ? v.w : 0.01f * v.w;
            }
            xs[lc + 0][lr + p * 32] = v.x;
            xs[lc + 1][lr + p * 32] = v.y;
            xs[lc + 2][lr + p * 32] = v.z;
            xs[lc + 3][lr + p * 32] = v.w;
        }
        // stage W tile (128 x 32), transposed into wsh[d][j]
#pragma unroll
        for (int p = 0; p < 4; ++p) {
            int j = p * 32 + lr;
            float4 v = *reinterpret_cast<const float4*>(&W[(size_t)j * 128 + k0 + lc]);
            wsh[lc + 0][j] = v.x;
            wsh[lc + 1][j] = v.y;
            wsh[lc + 2][j] = v.z;
            wsh[lc + 3][j] = v.w;
        }
        __syncthreads();

#pragma unroll
        for (int d = 0; d < 32; ++d) {
            const float4 b  = *reinterpret_cast<const float4*>(&wsh[d][tx * 4]);
            const float4 a0 = *reinterpret_cast<const float4*>(&xs[d][ty * 8]);
            const float4 a1 = *reinterpret_cast<const float4*>(&xs[d][ty * 8 + 4]);
            const float av[8] = {a0.x, a0.y, a0.z, a0.w, a1.x, a1.y, a1.z, a1.w};
            const float bv[4] = {b.x, b.y, b.z, b.w};
#pragma unroll
            for (int r = 0; r < 8; ++r)
#pragma unroll
                for (int c = 0; c < 4; ++c) acc[r][c] += av[r] * bv[c];
        }
        __syncthreads();
    }

#pragma unroll
    for (int r = 0; r < 8; ++r) {
        int row = m0 + ty * 8 + r;
        if (row < N) {
            float4 v = make_float4(acc[r][0], acc[r][1], acc[r][2], acc[r][3]);
            *reinterpret_cast<float4*>(&h[(size_t)row * 128 + tx * 4]) = v;
        }
    }
}

// ---------------------------------------------------------------------------
// el[n,h] = sum_f h[n,h,f]*attn_l[h,f]; er likewise. One wave per node.
// Feature index j in [0,128): head = j>>5. Lane covers j=lane and j=64+lane.
__global__ __launch_bounds__(256) void elr_kernel(
    const float* __restrict__ h, const float* __restrict__ al,
    const float* __restrict__ ar, float* __restrict__ el,
    float* __restrict__ er, int N)
{
    int node = blockIdx.x * 4 + (threadIdx.x >> 6);
    int lane = threadIdx.x & 63;
    if (node >= N) return;
    float v0 = h[(size_t)node * 128 + lane];
    float v1 = h[(size_t)node * 128 + 64 + lane];
    float sl0 = v0 * al[lane];
    float sl1 = v1 * al[64 + lane];
    float sr0 = v0 * ar[lane];
    float sr1 = v1 * ar[64 + lane];
#pragma unroll
    for (int m = 16; m >= 1; m >>= 1) {  // reduce within 32-lane halves
        sl0 += __shfl_xor(sl0, m, 64);
        sl1 += __shfl_xor(sl1, m, 64);
        sr0 += __shfl_xor(sr0, m, 64);
        sr1 += __shfl_xor(sr1, m, 64);
    }
    if ((lane & 31) == 0) {
        int hb = lane >> 5;  // 0 or 1
        el[node * 4 + hb]     = sl0;
        el[node * 4 + hb + 2] = sl1;
        er[node * 4 + hb]     = sr0;
        er[node * 4 + hb + 2] = sr1;
    }
}

// ---------------------------------------------------------------------------
// Per-dst softmax + aggregation. One wave per node. Lane covers features
// lane (head h0=lane>>5) and 64+lane (head h0+2).
__global__ __launch_bounds__(256) void agg_kernel(
    const float* __restrict__ h, const float* __restrict__ el,
    const float* __restrict__ er, const int* __restrict__ rowp,
    const int* __restrict__ col, const float* __restrict__ bias,
    float* __restrict__ xout, int N)
{
    int v = blockIdx.x * 4 + (threadIdx.x >> 6);
    int lane = threadIdx.x & 63;
    if (v >= N) return;
    int h0 = lane >> 5;
    float erv0 = er[v * 4 + h0];
    float erv1 = er[v * 4 + h0 + 2];
    int r0 = rowp[v], r1 = rowp[v + 1];

    float m0 = -INFINITY, m1 = -INFINITY, s0 = 0.f, s1 = 0.f;
    for (int j = r0; j < r1; ++j) {
        int u = col[j];
        float e0 = el[u * 4 + h0] + erv0;     e0 = e0 >= 0.f ? e0 : 0.2f * e0;
        float e1 = el[u * 4 + h0 + 2] + erv1; e1 = e1 >= 0.f ? e1 : 0.2f * e1;
        float nm0 = fmaxf(m0, e0);
        s0 = s0 * __expf(m0 - nm0) + __expf(e0 - nm0);
        m0 = nm0;
        float nm1 = fmaxf(m1, e1);
        s1 = s1 * __expf(m1 - nm1) + __expf(e1 - nm1);
        m1 = nm1;
    }
    float is0 = 1.f / s0, is1 = 1.f / s1;

    float acc0 = 0.f, acc1 = 0.f;
    for (int j = r0; j < r1; ++j) {
        int u = col[j];
        float e0 = el[u * 4 + h0] + erv0;     e0 = e0 >= 0.f ? e0 : 0.2f * e0;
        float e1 = el[u * 4 + h0 + 2] + erv1; e1 = e1 >= 0.f ? e1 : 0.2f * e1;
        float a0 = __expf(e0 - m0) * is0;
        float a1 = __expf(e1 - m1) * is1;
        acc0 += a0 * h[(size_t)u * 128 + lane];
        acc1 += a1 * h[(size_t)u * 128 + 64 + lane];
    }
    xout[(size_t)v * 128 + lane]      = acc0 + bias[lane];
    xout[(size_t)v * 128 + 64 + lane] = acc1 + bias[64 + lane];
}

// ---------------------------------------------------------------------------
// logits[n] = dot(x[n,:], pred_W) + pred_b. One wave per node.
__global__ __launch_bounds__(256) void pred_kernel(
    const float* __restrict__ x, const float* __restrict__ pW,
    const float* __restrict__ pb, float* __restrict__ out, int N)
{
    int v = blockIdx.x * 4 + (threadIdx.x >> 6);
    int lane = threadIdx.x & 63;
    if (v >= N) return;
    float s = x[(size_t)v * 128 + lane] * pW[lane]
            + x[(size_t)v * 128 + 64 + lane] * pW[64 + lane];
#pragma unroll
    for (int m = 32; m >= 1; m >>= 1) s += __shfl_xor(s, m, 64);
    if (lane == 0) out[v] = s + pb[0];
}

// ---------------------------------------------------------------------------
extern "C" void kernel_launch(void* const* d_in, const int* in_sizes, int n_in,
                              void* d_out, int out_size, void* d_ws, size_t ws_size,
                              hipStream_t stream)
{
    const float* weights = (const float*)d_in[0];
    const float* lin_W   = (const float*)d_in[1];
    const float* lin_b   = (const float*)d_in[2];
    const float* fc_W    = (const float*)d_in[3];
    const float* attn_l  = (const float*)d_in[4];
    const float* attn_r  = (const float*)d_in[5];
    const float* conv_b  = (const float*)d_in[6];
    const float* pred_W  = (const float*)d_in[7];
    const float* pred_b  = (const float*)d_in[8];
    const int*   src     = (const int*)d_in[9];
    const int*   dst     = (const int*)d_in[10];

    const int N = in_sizes[0];
    const int E = in_sizes[9];

    // workspace layout
    float* x  = (float*)d_ws;                    // N*128
    float* h  = x + (size_t)N * 128;             // N*128
    float* el = h + (size_t)N * 128;             // N*4
    float* er = el + (size_t)N * 4;              // N*4
    int*   deg  = (int*)(er + (size_t)N * 4);    // N
    int*   rowp = deg + N;                       // N+1
    int*   cur  = rowp + (N + 1);                // N
    int*   col  = cur + N;                       // E+N

    // CSR build (needed fresh every call: ws is re-poisoned)
    deg_init_kernel<<<(N + 255) / 256, 256, 0, stream>>>(deg, N);
    deg_count_kernel<<<(E + 255) / 256, 256, 0, stream>>>(dst, deg, E);
    scan_kernel<<<1, 1024, 0, stream>>>(deg, rowp, cur, N);
    scatter_kernel<<<(E + N + 255) / 256, 256, 0, stream>>>(src, dst, cur, col, E, N);

    // x init
    initx_kernel<<<((size_t)N * 128 + 255) / 256, 256, 0, stream>>>(weights, lin_W, lin_b, x, N);

    for (int l = 0; l < 3; ++l) {
        gemm_kernel<<<(N + 63) / 64, 256, 0, stream>>>(
            x, fc_W + (size_t)l * 128 * 128, h, N, l > 0 ? 1 : 0);
        elr_kernel<<<(N + 3) / 4, 256, 0, stream>>>(
            h, attn_l + l * 128, attn_r + l * 128, el, er, N);
        agg_kernel<<<(N + 3) / 4, 256, 0, stream>>>(
            h, el, er, rowp, col, conv_b + l * 128, x, N);
    }

    pred_kernel<<<(N + 3) / 4, 256, 0, stream>>>(x, pred_W, pred_b, (float*)d_out, N);
}

// Round 2
// 852.103 us; speedup vs baseline: 1.2604x; 1.2604x over previous
//
#include <hip/hip_runtime.h>
#include <hip/hip_bf16.h>
#include <math.h>

// Problem constants (match reference)
// N=100000, E=600000, D=128, H=4, F=32, L=3

// ---------------------------------------------------------------------------
// x init: x[n,d] = weights[n]*lin_W[d] + lin_b[d]
__global__ __launch_bounds__(256) void initx_kernel(
    const float* __restrict__ w, const float* __restrict__ lW,
    const float* __restrict__ lb, float* __restrict__ x, int N)
{
    int i = blockIdx.x * 256 + threadIdx.x;
    if (i >= N * 128) return;
    int n = i >> 7, d = i & 127;
    x[i] = w[n] * lW[d] + lb[d];
}

// ---------------------------------------------------------------------------
// CSR build
__global__ __launch_bounds__(256) void deg_init_kernel(int* __restrict__ deg, int N)
{
    int i = blockIdx.x * 256 + threadIdx.x;
    if (i < N) deg[i] = 1;  // self loop
}

__global__ __launch_bounds__(256) void deg_count_kernel(
    const int* __restrict__ dst, int* __restrict__ deg, int E)
{
    int i = blockIdx.x * 256 + threadIdx.x;
    if (i < E) atomicAdd(&deg[dst[i]], 1);
}

// ---- multi-block exclusive scan over deg[0..N) -> rowp, cur; rowp[N]=total
// Phase A: per-block sums (TILE=1024 elems per 256-thread block)
#define SCAN_TILE 1024

__global__ __launch_bounds__(256) void scanA_kernel(
    const int* __restrict__ deg, int* __restrict__ bsum, int N)
{
    __shared__ int ws[4];
    int b = blockIdx.x, t = threadIdx.x;
    int base = b * SCAN_TILE + t * 4;
    int s = 0;
#pragma unroll
    for (int k = 0; k < 4; ++k) {
        int i = base + k;
        if (i < N) s += deg[i];
    }
#pragma unroll
    for (int m = 32; m >= 1; m >>= 1) s += __shfl_xor(s, m, 64);
    if ((t & 63) == 0) ws[t >> 6] = s;
    __syncthreads();
    if (t == 0) bsum[b] = ws[0] + ws[1] + ws[2] + ws[3];
}

// Phase B: single small block scans NB block sums (NB <= 1024), exclusive.
__global__ __launch_bounds__(1024) void scanB_kernel(
    int* __restrict__ bsum, int* __restrict__ bpre, int* __restrict__ rowp,
    int NB, int N)
{
    __shared__ int sh[1024];
    int t = threadIdx.x;
    int v = (t < NB) ? bsum[t] : 0;
    sh[t] = v;
    __syncthreads();
    for (int off = 1; off < 1024; off <<= 1) {
        int u = (t >= off) ? sh[t - off] : 0;
        __syncthreads();
        sh[t] += u;
        __syncthreads();
    }
    if (t < NB) bpre[t] = sh[t] - v;          // exclusive prefix
    if (t == 1023) rowp[N] = sh[1023];        // total
}

// Phase C: per-block local exclusive scan + block offset; write rowp & cur.
__global__ __launch_bounds__(256) void scanC_kernel(
    const int* __restrict__ deg, const int* __restrict__ bpre,
    int* __restrict__ rowp, int* __restrict__ cur, int N)
{
    __shared__ int sh[256];
    int b = blockIdx.x, t = threadIdx.x;
    int base = b * SCAN_TILE + t * 4;
    int v[4];
#pragma unroll
    for (int k = 0; k < 4; ++k) {
        int i = base + k;
        v[k] = (i < N) ? deg[i] : 0;
    }
    int tsum = v[0] + v[1] + v[2] + v[3];
    sh[t] = tsum;
    __syncthreads();
    for (int off = 1; off < 256; off <<= 1) {
        int u = (t >= off) ? sh[t - off] : 0;
        __syncthreads();
        sh[t] += u;
        __syncthreads();
    }
    int pre = bpre[b] + sh[t] - tsum;  // exclusive across the block
#pragma unroll
    for (int k = 0; k < 4; ++k) {
        int i = base + k;
        if (i < N) { rowp[i] = pre; cur[i] = pre; }
        pre += v[k];
    }
}

__global__ __launch_bounds__(256) void scatter_kernel(
    const int* __restrict__ src, const int* __restrict__ dst,
    int* __restrict__ cur, int* __restrict__ col, int E, int N)
{
    int i = blockIdx.x * 256 + threadIdx.x;
    if (i < E) {
        int p = atomicAdd(&cur[dst[i]], 1);
        col[p] = src[i];
    } else if (i < E + N) {
        int v = i - E;
        int p = atomicAdd(&cur[v], 1);
        col[p] = v;  // self loop
    }
}

// ---------------------------------------------------------------------------
// GEMM: h[n,j] = sum_d act(x[n,d]) * W[j,d]   (W row-major [128,128])
// BM=64 rows, BN=128 cols (all), BK=32. 256 threads, 8x4 micro-tile.
__global__ __launch_bounds__(256) void gemm_kernel(
    const float* __restrict__ x, const float* __restrict__ W,
    float* __restrict__ h, int N, int leaky)
{
    __shared__ float xs[32][72];    // [d][row], padded
    __shared__ float wsh[32][132];  // [d][j], padded
    const int tid = threadIdx.x;
    const int m0 = blockIdx.x * 64;
    const int tx = tid & 31;   // col group: j = tx*4 .. +3
    const int ty = tid >> 5;   // row group: n = ty*8 .. +7

    float acc[8][4];
#pragma unroll
    for (int r = 0; r < 8; ++r)
#pragma unroll
        for (int c = 0; c < 4; ++c) acc[r][c] = 0.f;

    const int lr = tid >> 3;          // 0..31
    const int lc = (tid & 7) * 4;     // 0,4,...,28

    for (int k0 = 0; k0 < 128; k0 += 32) {
        // stage x tile (64 x 32), transposed into xs[d][row]
#pragma unroll
        for (int p = 0; p < 2; ++p) {
            int row = m0 + lr + p * 32;
            float4 v = make_float4(0.f, 0.f, 0.f, 0.f);
            if (row < N) v = *reinterpret_cast<const float4*>(&x[(size_t)row * 128 + k0 + lc]);
            if (leaky) {
                v.x = v.x >= 0.f ? v.x : 0.01f * v.x;
                v.y = v.y >= 0.f ? v.y : 0.01f * v.y;
                v.z = v.z >= 0.f ? v.z : 0.01f * v.z;
                v.w = v.w >= 0.f ? v.w : 0.01f * v.w;
            }
            xs[lc + 0][lr + p * 32] = v.x;
            xs[lc + 1][lr + p * 32] = v.y;
            xs[lc + 2][lr + p * 32] = v.z;
            xs[lc + 3][lr + p * 32] = v.w;
        }
        // stage W tile (128 x 32), transposed into wsh[d][j]
#pragma unroll
        for (int p = 0; p < 4; ++p) {
            int j = p * 32 + lr;
            float4 v = *reinterpret_cast<const float4*>(&W[(size_t)j * 128 + k0 + lc]);
            wsh[lc + 0][j] = v.x;
            wsh[lc + 1][j] = v.y;
            wsh[lc + 2][j] = v.z;
            wsh[lc + 3][j] = v.w;
        }
        __syncthreads();

#pragma unroll
        for (int d = 0; d < 32; ++d) {
            const float4 b  = *reinterpret_cast<const float4*>(&wsh[d][tx * 4]);
            const float4 a0 = *reinterpret_cast<const float4*>(&xs[d][ty * 8]);
            const float4 a1 = *reinterpret_cast<const float4*>(&xs[d][ty * 8 + 4]);
            const float av[8] = {a0.x, a0.y, a0.z, a0.w, a1.x, a1.y, a1.z, a1.w};
            const float bv[4] = {b.x, b.y, b.z, b.w};
#pragma unroll
            for (int r = 0; r < 8; ++r)
#pragma unroll
                for (int c = 0; c < 4; ++c) acc[r][c] += av[r] * bv[c];
        }
        __syncthreads();
    }

#pragma unroll
    for (int r = 0; r < 8; ++r) {
        int row = m0 + ty * 8 + r;
        if (row < N) {
            float4 v = make_float4(acc[r][0], acc[r][1], acc[r][2], acc[r][3]);
            *reinterpret_cast<float4*>(&h[(size_t)row * 128 + tx * 4]) = v;
        }
    }
}

// ---------------------------------------------------------------------------
// el[n,h] = sum_f h[n,h,f]*attn_l[h,f]; er likewise. One wave per node.
__global__ __launch_bounds__(256) void elr_kernel(
    const float* __restrict__ h, const float* __restrict__ al,
    const float* __restrict__ ar, float* __restrict__ el,
    float* __restrict__ er, int N)
{
    int node = blockIdx.x * 4 + (threadIdx.x >> 6);
    int lane = threadIdx.x & 63;
    if (node >= N) return;
    float v0 = h[(size_t)node * 128 + lane];
    float v1 = h[(size_t)node * 128 + 64 + lane];
    float sl0 = v0 * al[lane];
    float sl1 = v1 * al[64 + lane];
    float sr0 = v0 * ar[lane];
    float sr1 = v1 * ar[64 + lane];
#pragma unroll
    for (int m = 16; m >= 1; m >>= 1) {  // reduce within 32-lane halves
        sl0 += __shfl_xor(sl0, m, 64);
        sl1 += __shfl_xor(sl1, m, 64);
        sr0 += __shfl_xor(sr0, m, 64);
        sr1 += __shfl_xor(sr1, m, 64);
    }
    if ((lane & 31) == 0) {
        int hb = lane >> 5;  // 0 or 1
        el[node * 4 + hb]     = sl0;
        el[node * 4 + hb + 2] = sl1;
        er[node * 4 + hb]     = sr0;
        er[node * 4 + hb + 2] = sr1;
    }
}

// ---------------------------------------------------------------------------
// Per-dst softmax + aggregation. One wave per node.
__global__ __launch_bounds__(256) void agg_kernel(
    const float* __restrict__ h, const float* __restrict__ el,
    const float* __restrict__ er, const int* __restrict__ rowp,
    const int* __restrict__ col, const float* __restrict__ bias,
    float* __restrict__ xout, int N)
{
    int v = blockIdx.x * 4 + (threadIdx.x >> 6);
    int lane = threadIdx.x & 63;
    if (v >= N) return;
    int h0 = lane >> 5;
    float erv0 = er[v * 4 + h0];
    float erv1 = er[v * 4 + h0 + 2];
    int r0 = rowp[v], r1 = rowp[v + 1];

    float m0 = -INFINITY, m1 = -INFINITY, s0 = 0.f, s1 = 0.f;
    for (int j = r0; j < r1; ++j) {
        int u = col[j];
        float e0 = el[u * 4 + h0] + erv0;     e0 = e0 >= 0.f ? e0 : 0.2f * e0;
        float e1 = el[u * 4 + h0 + 2] + erv1; e1 = e1 >= 0.f ? e1 : 0.2f * e1;
        float nm0 = fmaxf(m0, e0);
        s0 = s0 * __expf(m0 - nm0) + __expf(e0 - nm0);
        m0 = nm0;
        float nm1 = fmaxf(m1, e1);
        s1 = s1 * __expf(m1 - nm1) + __expf(e1 - nm1);
        m1 = nm1;
    }
    float is0 = 1.f / s0, is1 = 1.f / s1;

    float acc0 = 0.f, acc1 = 0.f;
    for (int j = r0; j < r1; ++j) {
        int u = col[j];
        float e0 = el[u * 4 + h0] + erv0;     e0 = e0 >= 0.f ? e0 : 0.2f * e0;
        float e1 = el[u * 4 + h0 + 2] + erv1; e1 = e1 >= 0.f ? e1 : 0.2f * e1;
        float a0 = __expf(e0 - m0) * is0;
        float a1 = __expf(e1 - m1) * is1;
        acc0 += a0 * h[(size_t)u * 128 + lane];
        acc1 += a1 * h[(size_t)u * 128 + 64 + lane];
    }
    xout[(size_t)v * 128 + lane]      = acc0 + bias[lane];
    xout[(size_t)v * 128 + 64 + lane] = acc1 + bias[64 + lane];
}

// ---------------------------------------------------------------------------
// logits[n] = dot(x[n,:], pred_W) + pred_b. One wave per node.
__global__ __launch_bounds__(256) void pred_kernel(
    const float* __restrict__ x, const float* __restrict__ pW,
    const float* __restrict__ pb, float* __restrict__ out, int N)
{
    int v = blockIdx.x * 4 + (threadIdx.x >> 6);
    int lane = threadIdx.x & 63;
    if (v >= N) return;
    float s = x[(size_t)v * 128 + lane] * pW[lane]
            + x[(size_t)v * 128 + 64 + lane] * pW[64 + lane];
#pragma unroll
    for (int m = 32; m >= 1; m >>= 1) s += __shfl_xor(s, m, 64);
    if (lane == 0) out[v] = s + pb[0];
}

// ---------------------------------------------------------------------------
extern "C" void kernel_launch(void* const* d_in, const int* in_sizes, int n_in,
                              void* d_out, int out_size, void* d_ws, size_t ws_size,
                              hipStream_t stream)
{
    const float* weights = (const float*)d_in[0];
    const float* lin_W   = (const float*)d_in[1];
    const float* lin_b   = (const float*)d_in[2];
    const float* fc_W    = (const float*)d_in[3];
    const float* attn_l  = (const float*)d_in[4];
    const float* attn_r  = (const float*)d_in[5];
    const float* conv_b  = (const float*)d_in[6];
    const float* pred_W  = (const float*)d_in[7];
    const float* pred_b  = (const float*)d_in[8];
    const int*   src     = (const int*)d_in[9];
    const int*   dst     = (const int*)d_in[10];

    const int N = in_sizes[0];
    const int E = in_sizes[9];
    const int NB = (N + SCAN_TILE - 1) / SCAN_TILE;   // blocks for scan (98)

    // workspace layout
    float* x  = (float*)d_ws;                    // N*128
    float* h  = x + (size_t)N * 128;             // N*128
    float* el = h + (size_t)N * 128;             // N*4
    float* er = el + (size_t)N * 4;              // N*4
    int*   deg  = (int*)(er + (size_t)N * 4);    // N
    int*   rowp = deg + N;                       // N+1
    int*   cur  = rowp + (N + 1);                // N
    int*   col  = cur + N;                       // E+N
    int*   bsum = col + (E + N);                 // NB
    int*   bpre = bsum + NB;                     // NB

    // CSR build (fresh every call: ws is re-poisoned)
    deg_init_kernel<<<(N + 255) / 256, 256, 0, stream>>>(deg, N);
    deg_count_kernel<<<(E + 255) / 256, 256, 0, stream>>>(dst, deg, E);
    scanA_kernel<<<NB, 256, 0, stream>>>(deg, bsum, N);
    scanB_kernel<<<1, 1024, 0, stream>>>(bsum, bpre, rowp, NB, N);
    scanC_kernel<<<NB, 256, 0, stream>>>(deg, bpre, rowp, cur, N);
    scatter_kernel<<<(E + N + 255) / 256, 256, 0, stream>>>(src, dst, cur, col, E, N);

    // x init
    initx_kernel<<<((size_t)N * 128 + 255) / 256, 256, 0, stream>>>(weights, lin_W, lin_b, x, N);

    for (int l = 0; l < 3; ++l) {
        gemm_kernel<<<(N + 63) / 64, 256, 0, stream>>>(
            x, fc_W + (size_t)l * 128 * 128, h, N, l > 0 ? 1 : 0);
        elr_kernel<<<(N + 3) / 4, 256, 0, stream>>>(
            h, attn_l + l * 128, attn_r + l * 128, el, er, N);
        agg_kernel<<<(N + 3) / 4, 256, 0, stream>>>(
            h, el, er, rowp, col, conv_b + l * 128, x, N);
    }

    pred_kernel<<<(N + 3) / 4, 256, 0, stream>>>(x, pred_W, pred_b, (float*)d_out, N);
}

// Round 3
// 739.895 us; speedup vs baseline: 1.4516x; 1.1517x over previous
//
#include <hip/hip_runtime.h>
#include <hip/hip_bf16.h>
#include <math.h>

// Problem constants (match reference)
// N=100000, E=600000, D=128, H=4, F=32, L=3

__device__ __forceinline__ float leaky02(float x) {
    return x >= 0.f ? x : 0.2f * x;
}

// ---------------------------------------------------------------------------
// x init: x[n,d] = weights[n]*lin_W[d] + lin_b[d]
__global__ __launch_bounds__(256) void initx_kernel(
    const float* __restrict__ w, const float* __restrict__ lW,
    const float* __restrict__ lb, float* __restrict__ x, int N)
{
    int i = blockIdx.x * 256 + threadIdx.x;
    if (i >= N * 128) return;
    int n = i >> 7, d = i & 127;
    x[i] = w[n] * lW[d] + lb[d];
}

// ---------------------------------------------------------------------------
// CSR build
__global__ __launch_bounds__(256) void deg_init_kernel(int* __restrict__ deg, int N)
{
    int i = blockIdx.x * 256 + threadIdx.x;
    if (i < N) deg[i] = 1;  // self loop
}

__global__ __launch_bounds__(256) void deg_count_kernel(
    const int* __restrict__ dst, int* __restrict__ deg, int E)
{
    int i = blockIdx.x * 256 + threadIdx.x;
    if (i < E) atomicAdd(&deg[dst[i]], 1);
}

// ---- multi-block exclusive scan over deg[0..N) -> rowp, cur; rowp[N]=total
#define SCAN_TILE 1024

__global__ __launch_bounds__(256) void scanA_kernel(
    const int* __restrict__ deg, int* __restrict__ bsum, int N)
{
    __shared__ int ws[4];
    int b = blockIdx.x, t = threadIdx.x;
    int base = b * SCAN_TILE + t * 4;
    int s = 0;
#pragma unroll
    for (int k = 0; k < 4; ++k) {
        int i = base + k;
        if (i < N) s += deg[i];
    }
#pragma unroll
    for (int m = 32; m >= 1; m >>= 1) s += __shfl_xor(s, m, 64);
    if ((t & 63) == 0) ws[t >> 6] = s;
    __syncthreads();
    if (t == 0) bsum[b] = ws[0] + ws[1] + ws[2] + ws[3];
}

__global__ __launch_bounds__(1024) void scanB_kernel(
    int* __restrict__ bsum, int* __restrict__ bpre, int* __restrict__ rowp,
    int NB, int N)
{
    __shared__ int sh[1024];
    int t = threadIdx.x;
    int v = (t < NB) ? bsum[t] : 0;
    sh[t] = v;
    __syncthreads();
    for (int off = 1; off < 1024; off <<= 1) {
        int u = (t >= off) ? sh[t - off] : 0;
        __syncthreads();
        sh[t] += u;
        __syncthreads();
    }
    if (t < NB) bpre[t] = sh[t] - v;          // exclusive prefix
    if (t == 1023) rowp[N] = sh[1023];        // total
}

__global__ __launch_bounds__(256) void scanC_kernel(
    const int* __restrict__ deg, const int* __restrict__ bpre,
    int* __restrict__ rowp, int* __restrict__ cur, int N)
{
    __shared__ int sh[256];
    int b = blockIdx.x, t = threadIdx.x;
    int base = b * SCAN_TILE + t * 4;
    int v[4];
#pragma unroll
    for (int k = 0; k < 4; ++k) {
        int i = base + k;
        v[k] = (i < N) ? deg[i] : 0;
    }
    int tsum = v[0] + v[1] + v[2] + v[3];
    sh[t] = tsum;
    __syncthreads();
    for (int off = 1; off < 256; off <<= 1) {
        int u = (t >= off) ? sh[t - off] : 0;
        __syncthreads();
        sh[t] += u;
        __syncthreads();
    }
    int pre = bpre[b] + sh[t] - tsum;  // exclusive across the block
#pragma unroll
    for (int k = 0; k < 4; ++k) {
        int i = base + k;
        if (i < N) { rowp[i] = pre; cur[i] = pre; }
        pre += v[k];
    }
}

__global__ __launch_bounds__(256) void scatter_kernel(
    const int* __restrict__ src, const int* __restrict__ dst,
    int* __restrict__ cur, int* __restrict__ col, int E, int N)
{
    int i = blockIdx.x * 256 + threadIdx.x;
    if (i < E) {
        int p = atomicAdd(&cur[dst[i]], 1);
        col[p] = src[i];
    } else if (i < E + N) {
        int v = i - E;
        int p = atomicAdd(&cur[v], 1);
        col[p] = v;  // self loop
    }
}

// ---------------------------------------------------------------------------
// GEMM: h[n,j] = sum_d act(x[n,d]) * W[j,d]   (W row-major [128,128])
__global__ __launch_bounds__(256) void gemm_kernel(
    const float* __restrict__ x, const float* __restrict__ W,
    float* __restrict__ h, int N, int leaky)
{
    __shared__ float xs[32][72];    // [d][row], padded
    __shared__ float wsh[32][132];  // [d][j], padded
    const int tid = threadIdx.x;
    const int m0 = blockIdx.x * 64;
    const int tx = tid & 31;   // col group: j = tx*4 .. +3
    const int ty = tid >> 5;   // row group: n = ty*8 .. +7

    float acc[8][4];
#pragma unroll
    for (int r = 0; r < 8; ++r)
#pragma unroll
        for (int c = 0; c < 4; ++c) acc[r][c] = 0.f;

    const int lr = tid >> 3;          // 0..31
    const int lc = (tid & 7) * 4;     // 0,4,...,28

    for (int k0 = 0; k0 < 128; k0 += 32) {
#pragma unroll
        for (int p = 0; p < 2; ++p) {
            int row = m0 + lr + p * 32;
            float4 v = make_float4(0.f, 0.f, 0.f, 0.f);
            if (row < N) v = *reinterpret_cast<const float4*>(&x[(size_t)row * 128 + k0 + lc]);
            if (leaky) {
                v.x = v.x >= 0.f ? v.x : 0.01f * v.x;
                v.y = v.y >= 0.f ? v.y : 0.01f * v.y;
                v.z = v.z >= 0.f ? v.z : 0.01f * v.z;
                v.w = v.w >= 0.f ? v.w : 0.01f * v.w;
            }
            xs[lc + 0][lr + p * 32] = v.x;
            xs[lc + 1][lr + p * 32] = v.y;
            xs[lc + 2][lr + p * 32] = v.z;
            xs[lc + 3][lr + p * 32] = v.w;
        }
#pragma unroll
        for (int p = 0; p < 4; ++p) {
            int j = p * 32 + lr;
            float4 v = *reinterpret_cast<const float4*>(&W[(size_t)j * 128 + k0 + lc]);
            wsh[lc + 0][j] = v.x;
            wsh[lc + 1][j] = v.y;
            wsh[lc + 2][j] = v.z;
            wsh[lc + 3][j] = v.w;
        }
        __syncthreads();

#pragma unroll
        for (int d = 0; d < 32; ++d) {
            const float4 b  = *reinterpret_cast<const float4*>(&wsh[d][tx * 4]);
            const float4 a0 = *reinterpret_cast<const float4*>(&xs[d][ty * 8]);
            const float4 a1 = *reinterpret_cast<const float4*>(&xs[d][ty * 8 + 4]);
            const float av[8] = {a0.x, a0.y, a0.z, a0.w, a1.x, a1.y, a1.z, a1.w};
            const float bv[4] = {b.x, b.y, b.z, b.w};
#pragma unroll
            for (int r = 0; r < 8; ++r)
#pragma unroll
                for (int c = 0; c < 4; ++c) acc[r][c] += av[r] * bv[c];
        }
        __syncthreads();
    }

#pragma unroll
    for (int r = 0; r < 8; ++r) {
        int row = m0 + ty * 8 + r;
        if (row < N) {
            float4 v = make_float4(acc[r][0], acc[r][1], acc[r][2], acc[r][3]);
            *reinterpret_cast<float4*>(&h[(size_t)row * 128 + tx * 4]) = v;
        }
    }
}

// ---------------------------------------------------------------------------
// el[n,h] = sum_f h[n,h,f]*attn_l[h,f]; er likewise. One wave per node.
__global__ __launch_bounds__(256) void elr_kernel(
    const float* __restrict__ h, const float* __restrict__ al,
    const float* __restrict__ ar, float* __restrict__ el,
    float* __restrict__ er, int N)
{
    int node = blockIdx.x * 4 + (threadIdx.x >> 6);
    int lane = threadIdx.x & 63;
    if (node >= N) return;
    float v0 = h[(size_t)node * 128 + lane];
    float v1 = h[(size_t)node * 128 + 64 + lane];
    float sl0 = v0 * al[lane];
    float sl1 = v1 * al[64 + lane];
    float sr0 = v0 * ar[lane];
    float sr1 = v1 * ar[64 + lane];
#pragma unroll
    for (int m = 16; m >= 1; m >>= 1) {  // reduce within 32-lane halves
        sl0 += __shfl_xor(sl0, m, 64);
        sl1 += __shfl_xor(sl1, m, 64);
        sr0 += __shfl_xor(sr0, m, 64);
        sr1 += __shfl_xor(sr1, m, 64);
    }
    if ((lane & 31) == 0) {
        int hb = lane >> 5;  // 0 or 1
        el[node * 4 + hb]     = sl0;
        el[node * 4 + hb + 2] = sl1;
        er[node * 4 + hb]     = sr0;
        er[node * 4 + hb + 2] = sr1;
    }
}

// ---------------------------------------------------------------------------
// Softmax stats: one wave per node, LANE-PARALLEL over incoming edges.
// Each lane handles one edge (all 4 heads via float4 el load); shuffle-reduce
// max & sum; store per-node m[4] and 1/s[4] into ms[v*8 .. v*8+7].
__global__ __launch_bounds__(256) void stats_kernel(
    const float* __restrict__ el, const float* __restrict__ er,
    const int* __restrict__ rowp, const int* __restrict__ col,
    float* __restrict__ ms, int N)
{
    int v = blockIdx.x * 4 + (threadIdx.x >> 6);
    int lane = threadIdx.x & 63;
    if (v >= N) return;
    const float4 erv = *reinterpret_cast<const float4*>(&er[(size_t)v * 4]);
    int r0 = rowp[v], r1 = rowp[v + 1];

    float m[4] = {-INFINITY, -INFINITY, -INFINITY, -INFINITY};
    float s[4] = {0.f, 0.f, 0.f, 0.f};

    for (int base = r0; base < r1; base += 64) {
        int j = base + lane;
        bool act = j < r1;
        float e[4];
        if (act) {
            int u = col[j];
            float4 elu = *reinterpret_cast<const float4*>(&el[(size_t)u * 4]);
            e[0] = leaky02(elu.x + erv.x);
            e[1] = leaky02(elu.y + erv.y);
            e[2] = leaky02(elu.z + erv.z);
            e[3] = leaky02(elu.w + erv.w);
        } else {
            e[0] = e[1] = e[2] = e[3] = -INFINITY;
        }
#pragma unroll
        for (int hh = 0; hh < 4; ++hh) {
            float cm = e[hh];
#pragma unroll
            for (int d = 32; d >= 1; d >>= 1) cm = fmaxf(cm, __shfl_xor(cm, d, 64));
            float ce = act ? __expf(e[hh] - cm) : 0.f;
#pragma unroll
            for (int d = 32; d >= 1; d >>= 1) ce += __shfl_xor(ce, d, 64);
            float nm = fmaxf(m[hh], cm);
            s[hh] = s[hh] * __expf(m[hh] - nm) + ce * __expf(cm - nm);
            m[hh] = nm;
        }
    }
    if (lane == 0) {
        float4 mv = make_float4(m[0], m[1], m[2], m[3]);
        float4 iv = make_float4(1.f / s[0], 1.f / s[1], 1.f / s[2], 1.f / s[3]);
        *reinterpret_cast<float4*>(&ms[(size_t)v * 8])     = mv;
        *reinterpret_cast<float4*>(&ms[(size_t)v * 8 + 4]) = iv;
    }
}

// ---------------------------------------------------------------------------
// Gather+aggregate: one wave per node, 4 edges in flight per iteration
// (quarter-wave of 16 lanes per edge). Lane l16 covers features f0=l16*4
// (heads 0/1 slot) and 64+f0 (heads 2/3 slot) -> 2 float4 h loads per lane.
__global__ __launch_bounds__(256) void agg_gather_kernel(
    const float* __restrict__ h, const float* __restrict__ el,
    const float* __restrict__ er, const float* __restrict__ ms,
    const int* __restrict__ rowp, const int* __restrict__ col,
    const float* __restrict__ bias, float* __restrict__ xout, int N)
{
    int v = blockIdx.x * 4 + (threadIdx.x >> 6);
    int lane = threadIdx.x & 63;
    if (v >= N) return;
    const int q    = lane >> 4;      // quarter 0..3 -> edge slot
    const int l16  = lane & 15;
    const int f0   = l16 * 4;        // 0..60
    const int hA   = l16 >> 3;       // head for acc0: 0 or 1
    // per-lane softmax params for its two head slots
    float erA = er[(size_t)v * 4 + hA];
    float erB = er[(size_t)v * 4 + 2 + hA];
    float mA  = ms[(size_t)v * 8 + hA];
    float mB  = ms[(size_t)v * 8 + 2 + hA];
    float isA = ms[(size_t)v * 8 + 4 + hA];
    float isB = ms[(size_t)v * 8 + 6 + hA];

    int r0 = rowp[v], r1 = rowp[v + 1];
    float4 acc0 = make_float4(0.f, 0.f, 0.f, 0.f);
    float4 acc1 = make_float4(0.f, 0.f, 0.f, 0.f);

    for (int jb = r0; jb < r1; jb += 4) {
        int j = jb + q;
        if (j < r1) {
            int u = col[j];
            float eA = leaky02(el[(size_t)u * 4 + hA] + erA);
            float eB = leaky02(el[(size_t)u * 4 + 2 + hA] + erB);
            float aA = __expf(eA - mA) * isA;
            float aB = __expf(eB - mB) * isB;
            float4 v0 = *reinterpret_cast<const float4*>(&h[(size_t)u * 128 + f0]);
            float4 v1 = *reinterpret_cast<const float4*>(&h[(size_t)u * 128 + 64 + f0]);
            acc0.x += aA * v0.x; acc0.y += aA * v0.y;
            acc0.z += aA * v0.z; acc0.w += aA * v0.w;
            acc1.x += aB * v1.x; acc1.y += aB * v1.y;
            acc1.z += aB * v1.z; acc1.w += aB * v1.w;
        }
    }
    // combine the 4 quarter-wave partials (lanes l, l^16, l^32, l^48)
#pragma unroll
    for (int d = 16; d <= 32; d <<= 1) {
        acc0.x += __shfl_xor(acc0.x, d, 64);
        acc0.y += __shfl_xor(acc0.y, d, 64);
        acc0.z += __shfl_xor(acc0.z, d, 64);
        acc0.w += __shfl_xor(acc0.w, d, 64);
        acc1.x += __shfl_xor(acc1.x, d, 64);
        acc1.y += __shfl_xor(acc1.y, d, 64);
        acc1.z += __shfl_xor(acc1.z, d, 64);
        acc1.w += __shfl_xor(acc1.w, d, 64);
    }
    if (lane < 16) {
        float4 b0 = *reinterpret_cast<const float4*>(&bias[f0]);
        float4 b1 = *reinterpret_cast<const float4*>(&bias[64 + f0]);
        acc0.x += b0.x; acc0.y += b0.y; acc0.z += b0.z; acc0.w += b0.w;
        acc1.x += b1.x; acc1.y += b1.y; acc1.z += b1.z; acc1.w += b1.w;
        *reinterpret_cast<float4*>(&xout[(size_t)v * 128 + f0])      = acc0;
        *reinterpret_cast<float4*>(&xout[(size_t)v * 128 + 64 + f0]) = acc1;
    }
}

// ---------------------------------------------------------------------------
// logits[n] = dot(x[n,:], pred_W) + pred_b. One wave per node.
__global__ __launch_bounds__(256) void pred_kernel(
    const float* __restrict__ x, const float* __restrict__ pW,
    const float* __restrict__ pb, float* __restrict__ out, int N)
{
    int v = blockIdx.x * 4 + (threadIdx.x >> 6);
    int lane = threadIdx.x & 63;
    if (v >= N) return;
    float s = x[(size_t)v * 128 + lane] * pW[lane]
            + x[(size_t)v * 128 + 64 + lane] * pW[64 + lane];
#pragma unroll
    for (int m = 32; m >= 1; m >>= 1) s += __shfl_xor(s, m, 64);
    if (lane == 0) out[v] = s + pb[0];
}

// ---------------------------------------------------------------------------
extern "C" void kernel_launch(void* const* d_in, const int* in_sizes, int n_in,
                              void* d_out, int out_size, void* d_ws, size_t ws_size,
                              hipStream_t stream)
{
    const float* weights = (const float*)d_in[0];
    const float* lin_W   = (const float*)d_in[1];
    const float* lin_b   = (const float*)d_in[2];
    const float* fc_W    = (const float*)d_in[3];
    const float* attn_l  = (const float*)d_in[4];
    const float* attn_r  = (const float*)d_in[5];
    const float* conv_b  = (const float*)d_in[6];
    const float* pred_W  = (const float*)d_in[7];
    const float* pred_b  = (const float*)d_in[8];
    const int*   src     = (const int*)d_in[9];
    const int*   dst     = (const int*)d_in[10];

    const int N = in_sizes[0];
    const int E = in_sizes[9];
    const int NB = (N + SCAN_TILE - 1) / SCAN_TILE;

    // workspace layout (floats first to keep 16B alignment for float4 use)
    float* x  = (float*)d_ws;                    // N*128
    float* h  = x + (size_t)N * 128;             // N*128
    float* el = h + (size_t)N * 128;             // N*4
    float* er = el + (size_t)N * 4;              // N*4
    float* ms = er + (size_t)N * 4;              // N*8  (m[4], 1/s[4] per node)
    int*   deg  = (int*)(ms + (size_t)N * 8);    // N
    int*   rowp = deg + N;                       // N+1
    int*   cur  = rowp + (N + 1);                // N
    int*   col  = cur + N;                       // E+N
    int*   bsum = col + (E + N);                 // NB
    int*   bpre = bsum + NB;                     // NB

    // CSR build (fresh every call: ws is re-poisoned)
    deg_init_kernel<<<(N + 255) / 256, 256, 0, stream>>>(deg, N);
    deg_count_kernel<<<(E + 255) / 256, 256, 0, stream>>>(dst, deg, E);
    scanA_kernel<<<NB, 256, 0, stream>>>(deg, bsum, N);
    scanB_kernel<<<1, 1024, 0, stream>>>(bsum, bpre, rowp, NB, N);
    scanC_kernel<<<NB, 256, 0, stream>>>(deg, bpre, rowp, cur, N);
    scatter_kernel<<<(E + N + 255) / 256, 256, 0, stream>>>(src, dst, cur, col, E, N);

    // x init
    initx_kernel<<<((size_t)N * 128 + 255) / 256, 256, 0, stream>>>(weights, lin_W, lin_b, x, N);

    for (int l = 0; l < 3; ++l) {
        gemm_kernel<<<(N + 63) / 64, 256, 0, stream>>>(
            x, fc_W + (size_t)l * 128 * 128, h, N, l > 0 ? 1 : 0);
        elr_kernel<<<(N + 3) / 4, 256, 0, stream>>>(
            h, attn_l + l * 128, attn_r + l * 128, el, er, N);
        stats_kernel<<<(N + 3) / 4, 256, 0, stream>>>(
            el, er, rowp, col, ms, N);
        agg_gather_kernel<<<(N + 3) / 4, 256, 0, stream>>>(
            h, el, er, ms, rowp, col, conv_b + l * 128, x, N);
    }

    pred_kernel<<<(N + 3) / 4, 256, 0, stream>>>(x, pred_W, pred_b, (float*)d_out, N);
}

// Round 4
// 623.042 us; speedup vs baseline: 1.7238x; 1.1876x over previous
//
#include <hip/hip_runtime.h>
#include <hip/hip_bf16.h>
#include <math.h>

// Problem constants: N=100000, E=600000, D=128, H=4, F=32, L=3

__device__ __forceinline__ float leaky02(float x) {
    return x >= 0.f ? x : 0.2f * x;
}

// ---------------------------------------------------------------------------
// CSR build
__global__ __launch_bounds__(256) void deg_init_kernel(int* __restrict__ deg, int N)
{
    int i = blockIdx.x * 256 + threadIdx.x;
    if (i < N) deg[i] = 1;  // self loop
}

__global__ __launch_bounds__(256) void deg_count_kernel(
    const int* __restrict__ dst, int* __restrict__ deg, int E)
{
    int i = blockIdx.x * 256 + threadIdx.x;
    if (i < E) atomicAdd(&deg[dst[i]], 1);
}

#define SCAN_TILE 1024

__global__ __launch_bounds__(256) void scanA_kernel(
    const int* __restrict__ deg, int* __restrict__ bsum, int N)
{
    __shared__ int ws[4];
    int b = blockIdx.x, t = threadIdx.x;
    int base = b * SCAN_TILE + t * 4;
    int s = 0;
#pragma unroll
    for (int k = 0; k < 4; ++k) {
        int i = base + k;
        if (i < N) s += deg[i];
    }
#pragma unroll
    for (int m = 32; m >= 1; m >>= 1) s += __shfl_xor(s, m, 64);
    if ((t & 63) == 0) ws[t >> 6] = s;
    __syncthreads();
    if (t == 0) bsum[b] = ws[0] + ws[1] + ws[2] + ws[3];
}

__global__ __launch_bounds__(1024) void scanB_kernel(
    int* __restrict__ bsum, int* __restrict__ bpre, int* __restrict__ rowp,
    int NB, int N)
{
    __shared__ int sh[1024];
    int t = threadIdx.x;
    int v = (t < NB) ? bsum[t] : 0;
    sh[t] = v;
    __syncthreads();
    for (int off = 1; off < 1024; off <<= 1) {
        int u = (t >= off) ? sh[t - off] : 0;
        __syncthreads();
        sh[t] += u;
        __syncthreads();
    }
    if (t < NB) bpre[t] = sh[t] - v;          // exclusive prefix
    if (t == 1023) rowp[N] = sh[1023];        // total
}

__global__ __launch_bounds__(256) void scanC_kernel(
    const int* __restrict__ deg, const int* __restrict__ bpre,
    int* __restrict__ rowp, int* __restrict__ cur, int N)
{
    __shared__ int sh[256];
    int b = blockIdx.x, t = threadIdx.x;
    int base = b * SCAN_TILE + t * 4;
    int v[4];
#pragma unroll
    for (int k = 0; k < 4; ++k) {
        int i = base + k;
        v[k] = (i < N) ? deg[i] : 0;
    }
    int tsum = v[0] + v[1] + v[2] + v[3];
    sh[t] = tsum;
    __syncthreads();
    for (int off = 1; off < 256; off <<= 1) {
        int u = (t >= off) ? sh[t - off] : 0;
        __syncthreads();
        sh[t] += u;
        __syncthreads();
    }
    int pre = bpre[b] + sh[t] - tsum;
#pragma unroll
    for (int k = 0; k < 4; ++k) {
        int i = base + k;
        if (i < N) { rowp[i] = pre; cur[i] = pre; }
        pre += v[k];
    }
}

__global__ __launch_bounds__(256) void scatter_kernel(
    const int* __restrict__ src, const int* __restrict__ dst,
    int* __restrict__ cur, int* __restrict__ col, int E, int N)
{
    int i = blockIdx.x * 256 + threadIdx.x;
    if (i < E) {
        int p = atomicAdd(&cur[dst[i]], 1);
        col[p] = src[i];
    } else if (i < E + N) {
        int v = i - E;
        int p = atomicAdd(&cur[v], 1);
        col[p] = v;  // self loop
    }
}

// ---------------------------------------------------------------------------
// Layer-0 rank-1 precompute:
// c1[j] = sum_d lin_W[d] * W0[j,d];  c2[j] = sum_d lin_b[d] * W0[j,d]
// pl[h] = sum_f c1[h*32+f]*al[h*32+f], ql[h] = sum_f c2*al, pr/qr with ar.
// prm = [pl(4), ql(4), pr(4), qr(4)]
__global__ __launch_bounds__(128) void rank1_prep_kernel(
    const float* __restrict__ lW, const float* __restrict__ lb,
    const float* __restrict__ W0, const float* __restrict__ al,
    const float* __restrict__ ar, float* __restrict__ c1,
    float* __restrict__ c2, float* __restrict__ prm)
{
    int j = threadIdx.x;
    float s1 = 0.f, s2 = 0.f;
    for (int d = 0; d < 128; ++d) {
        float wv = W0[j * 128 + d];
        s1 += lW[d] * wv;
        s2 += lb[d] * wv;
    }
    c1[j] = s1; c2[j] = s2;
    __shared__ float sh1[128], sh2[128], sh3[128], sh4[128];
    sh1[j] = s1 * al[j]; sh2[j] = s2 * al[j];
    sh3[j] = s1 * ar[j]; sh4[j] = s2 * ar[j];
    __syncthreads();
    if (j < 4) {
        float p = 0.f, q = 0.f, r = 0.f, s = 0.f;
        for (int f = 0; f < 32; ++f) {
            p += sh1[j * 32 + f]; q += sh2[j * 32 + f];
            r += sh3[j * 32 + f]; s += sh4[j * 32 + f];
        }
        prm[j] = p; prm[4 + j] = q; prm[8 + j] = r; prm[12 + j] = s;
    }
}

// h0[n,j] = w[n]*c1[j] + c2[j]; el0[n,h] = w[n]*pl[h]+ql[h]; er0 likewise.
__global__ __launch_bounds__(256) void rank1_apply_kernel(
    const float* __restrict__ w, const float* __restrict__ c1,
    const float* __restrict__ c2, const float* __restrict__ prm,
    float* __restrict__ h, float* __restrict__ el, float* __restrict__ er, int N)
{
    int i = blockIdx.x * 256 + threadIdx.x;
    int n = i >> 5, k = i & 31;
    if (n >= N) return;
    float wn = w[n];
    float4 a = *reinterpret_cast<const float4*>(&c1[k * 4]);
    float4 b = *reinterpret_cast<const float4*>(&c2[k * 4]);
    float4 o = make_float4(wn * a.x + b.x, wn * a.y + b.y,
                           wn * a.z + b.z, wn * a.w + b.w);
    *reinterpret_cast<float4*>(&h[(size_t)n * 128 + k * 4]) = o;
    if (k == 0) {
        float4 pl = *reinterpret_cast<const float4*>(&prm[0]);
        float4 ql = *reinterpret_cast<const float4*>(&prm[4]);
        float4 pr = *reinterpret_cast<const float4*>(&prm[8]);
        float4 qr = *reinterpret_cast<const float4*>(&prm[12]);
        float4 e1 = make_float4(wn * pl.x + ql.x, wn * pl.y + ql.y,
                                wn * pl.z + ql.z, wn * pl.w + ql.w);
        float4 e2 = make_float4(wn * pr.x + qr.x, wn * pr.y + qr.y,
                                wn * pr.z + qr.z, wn * pr.w + qr.w);
        *reinterpret_cast<float4*>(&el[(size_t)n * 4]) = e1;
        *reinterpret_cast<float4*>(&er[(size_t)n * 4]) = e2;
    }
}

// ---------------------------------------------------------------------------
// GEMM (layers 1,2): h[n,j] = sum_d leaky0.01(x[n,d]) * W[j,d]
// 128x128 tile, BK=32, 256 threads, 8x8 micro-tile (cols split lo/hi 64).
__global__ __launch_bounds__(256) void gemm_kernel(
    const float* __restrict__ x, const float* __restrict__ W,
    float* __restrict__ h, int N)
{
    __shared__ float xs[32][132];    // [d][row in tile], 132*4B = 16B-mult
    __shared__ float wsh[32][132];   // [d][j]
    const int tid = threadIdx.x;
    const int m0 = blockIdx.x * 128;
    const int tx = tid & 15;         // col group
    const int ty = tid >> 4;         // row group 0..15
    const int lr = tid >> 3;         // staging row 0..31
    const int lc = (tid & 7) * 4;    // staging col (float4 of K-panel)

    float acc[8][8];
#pragma unroll
    for (int r = 0; r < 8; ++r)
#pragma unroll
        for (int c = 0; c < 8; ++c) acc[r][c] = 0.f;

    for (int k0 = 0; k0 < 128; k0 += 32) {
#pragma unroll
        for (int p = 0; p < 4; ++p) {
            int row = m0 + lr + p * 32;
            float4 v = make_float4(0.f, 0.f, 0.f, 0.f);
            if (row < N) v = *reinterpret_cast<const float4*>(&x[(size_t)row * 128 + k0 + lc]);
            v.x = v.x >= 0.f ? v.x : 0.01f * v.x;
            v.y = v.y >= 0.f ? v.y : 0.01f * v.y;
            v.z = v.z >= 0.f ? v.z : 0.01f * v.z;
            v.w = v.w >= 0.f ? v.w : 0.01f * v.w;
            xs[lc + 0][lr + p * 32] = v.x;
            xs[lc + 1][lr + p * 32] = v.y;
            xs[lc + 2][lr + p * 32] = v.z;
            xs[lc + 3][lr + p * 32] = v.w;
        }
#pragma unroll
        for (int p = 0; p < 4; ++p) {
            int j = lr + p * 32;
            float4 v = *reinterpret_cast<const float4*>(&W[(size_t)j * 128 + k0 + lc]);
            wsh[lc + 0][j] = v.x;
            wsh[lc + 1][j] = v.y;
            wsh[lc + 2][j] = v.z;
            wsh[lc + 3][j] = v.w;
        }
        __syncthreads();

#pragma unroll
        for (int d = 0; d < 32; ++d) {
            const float4 a0 = *reinterpret_cast<const float4*>(&xs[d][ty * 8]);
            const float4 a1 = *reinterpret_cast<const float4*>(&xs[d][ty * 8 + 4]);
            const float4 b0 = *reinterpret_cast<const float4*>(&wsh[d][tx * 4]);
            const float4 b1 = *reinterpret_cast<const float4*>(&wsh[d][64 + tx * 4]);
            const float av[8] = {a0.x, a0.y, a0.z, a0.w, a1.x, a1.y, a1.z, a1.w};
            const float bv[8] = {b0.x, b0.y, b0.z, b0.w, b1.x, b1.y, b1.z, b1.w};
#pragma unroll
            for (int r = 0; r < 8; ++r)
#pragma unroll
                for (int c = 0; c < 8; ++c) acc[r][c] += av[r] * bv[c];
        }
        __syncthreads();
    }

#pragma unroll
    for (int r = 0; r < 8; ++r) {
        int row = m0 + ty * 8 + r;
        if (row < N) {
            float4 lo = make_float4(acc[r][0], acc[r][1], acc[r][2], acc[r][3]);
            float4 hi = make_float4(acc[r][4], acc[r][5], acc[r][6], acc[r][7]);
            *reinterpret_cast<float4*>(&h[(size_t)row * 128 + tx * 4])      = lo;
            *reinterpret_cast<float4*>(&h[(size_t)row * 128 + 64 + tx * 4]) = hi;
        }
    }
}

// ---------------------------------------------------------------------------
// el/er reduction (layers 1,2). One wave per node.
__global__ __launch_bounds__(256) void elr_kernel(
    const float* __restrict__ h, const float* __restrict__ al,
    const float* __restrict__ ar, float* __restrict__ el,
    float* __restrict__ er, int N)
{
    int node = blockIdx.x * 4 + (threadIdx.x >> 6);
    int lane = threadIdx.x & 63;
    if (node >= N) return;
    float v0 = h[(size_t)node * 128 + lane];
    float v1 = h[(size_t)node * 128 + 64 + lane];
    float sl0 = v0 * al[lane];
    float sl1 = v1 * al[64 + lane];
    float sr0 = v0 * ar[lane];
    float sr1 = v1 * ar[64 + lane];
#pragma unroll
    for (int m = 16; m >= 1; m >>= 1) {
        sl0 += __shfl_xor(sl0, m, 64);
        sl1 += __shfl_xor(sl1, m, 64);
        sr0 += __shfl_xor(sr0, m, 64);
        sr1 += __shfl_xor(sr1, m, 64);
    }
    if ((lane & 31) == 0) {
        int hb = lane >> 5;
        el[node * 4 + hb]     = sl0;
        el[node * 4 + hb + 2] = sl1;
        er[node * 4 + hb]     = sr0;
        er[node * 4 + hb + 2] = sr1;
    }
}

// ---------------------------------------------------------------------------
// Fused softmax-stats + gather + (optional) prediction epilogue.
// One wave per node.
// Phase A: lane-parallel online softmax over incoming edges -> m[4], is[4].
// Phase B: per 64-edge chunk, lane j computes alpha[4] for edge j; quarter-
//          waves (16 lanes) gather 4 edges/iter, alpha broadcast via shfl.
// Epilogue: last=0 -> xout[v,:] = acc + bias; last=1 -> logits[v] =
//          dot(acc+bias, pW) + pb.
__global__ __launch_bounds__(256) void agg_fused_kernel(
    const float* __restrict__ h, const float* __restrict__ el,
    const float* __restrict__ er, const int* __restrict__ rowp,
    const int* __restrict__ col, const float* __restrict__ bias,
    float* __restrict__ xout, const float* __restrict__ pW,
    const float* __restrict__ pb, float* __restrict__ logits,
    int N, int last)
{
    int v = blockIdx.x * 4 + (threadIdx.x >> 6);
    int lane = threadIdx.x & 63;
    if (v >= N) return;
    const float4 erv = *reinterpret_cast<const float4*>(&er[(size_t)v * 4]);
    const int r0 = rowp[v], r1 = rowp[v + 1];

    // ---- Phase A: online softmax stats
    float m[4] = {-INFINITY, -INFINITY, -INFINITY, -INFINITY};
    float s[4] = {0.f, 0.f, 0.f, 0.f};
    for (int base = r0; base < r1; base += 64) {
        int j = base + lane;
        bool act = j < r1;
        float e[4];
        if (act) {
            int u = col[j];
            float4 elu = *reinterpret_cast<const float4*>(&el[(size_t)u * 4]);
            e[0] = leaky02(elu.x + erv.x);
            e[1] = leaky02(elu.y + erv.y);
            e[2] = leaky02(elu.z + erv.z);
            e[3] = leaky02(elu.w + erv.w);
        } else {
            e[0] = e[1] = e[2] = e[3] = -INFINITY;
        }
#pragma unroll
        for (int hh = 0; hh < 4; ++hh) {
            float cm = e[hh];
#pragma unroll
            for (int d = 32; d >= 1; d >>= 1) cm = fmaxf(cm, __shfl_xor(cm, d, 64));
            float ce = act ? __expf(e[hh] - cm) : 0.f;
#pragma unroll
            for (int d = 32; d >= 1; d >>= 1) ce += __shfl_xor(ce, d, 64);
            float nm = fmaxf(m[hh], cm);
            s[hh] = s[hh] * __expf(m[hh] - nm) + ce * __expf(cm - nm);
            m[hh] = nm;
        }
    }
    float is[4] = {1.f / s[0], 1.f / s[1], 1.f / s[2], 1.f / s[3]};

    // ---- Phase B: gather
    const int q = lane >> 4, l16 = lane & 15, f0 = l16 * 4, hA = l16 >> 3;
    float4 acc0 = make_float4(0.f, 0.f, 0.f, 0.f);
    float4 acc1 = make_float4(0.f, 0.f, 0.f, 0.f);

    for (int base = r0; base < r1; base += 64) {
        int cnt = r1 - base; if (cnt > 64) cnt = 64;
        int u = 0;
        float a0 = 0.f, a1 = 0.f, a2 = 0.f, a3 = 0.f;
        if (lane < cnt) {
            u = col[base + lane];
            float4 elu = *reinterpret_cast<const float4*>(&el[(size_t)u * 4]);
            a0 = __expf(leaky02(elu.x + erv.x) - m[0]) * is[0];
            a1 = __expf(leaky02(elu.y + erv.y) - m[1]) * is[1];
            a2 = __expf(leaky02(elu.z + erv.z) - m[2]) * is[2];
            a3 = __expf(leaky02(elu.w + erv.w) - m[3]) * is[3];
        }
        for (int jb = 0; jb < cnt; jb += 4) {
            int sl = jb + q;
            int uu   = __shfl(u,  sl, 64);
            float s0 = __shfl(a0, sl, 64);
            float s1 = __shfl(a1, sl, 64);
            float s2 = __shfl(a2, sl, 64);
            float s3 = __shfl(a3, sl, 64);
            if (sl < cnt) {
                float aA = hA ? s1 : s0;
                float aB = hA ? s3 : s2;
                const float4 v0 = *reinterpret_cast<const float4*>(&h[(size_t)uu * 128 + f0]);
                const float4 v1 = *reinterpret_cast<const float4*>(&h[(size_t)uu * 128 + 64 + f0]);
                acc0.x += aA * v0.x; acc0.y += aA * v0.y;
                acc0.z += aA * v0.z; acc0.w += aA * v0.w;
                acc1.x += aB * v1.x; acc1.y += aB * v1.y;
                acc1.z += aB * v1.z; acc1.w += aB * v1.w;
            }
        }
    }

    // combine quarter-wave partials (lanes l, l^16, l^32, l^48)
#pragma unroll
    for (int d = 16; d <= 32; d <<= 1) {
        acc0.x += __shfl_xor(acc0.x, d, 64);
        acc0.y += __shfl_xor(acc0.y, d, 64);
        acc0.z += __shfl_xor(acc0.z, d, 64);
        acc0.w += __shfl_xor(acc0.w, d, 64);
        acc1.x += __shfl_xor(acc1.x, d, 64);
        acc1.y += __shfl_xor(acc1.y, d, 64);
        acc1.z += __shfl_xor(acc1.z, d, 64);
        acc1.w += __shfl_xor(acc1.w, d, 64);
    }

    if (last) {
        float part = 0.f;
        if (lane < 16) {
            float4 b0 = *reinterpret_cast<const float4*>(&bias[f0]);
            float4 b1 = *reinterpret_cast<const float4*>(&bias[64 + f0]);
            float4 p0 = *reinterpret_cast<const float4*>(&pW[f0]);
            float4 p1 = *reinterpret_cast<const float4*>(&pW[64 + f0]);
            part = (acc0.x + b0.x) * p0.x + (acc0.y + b0.y) * p0.y
                 + (acc0.z + b0.z) * p0.z + (acc0.w + b0.w) * p0.w
                 + (acc1.x + b1.x) * p1.x + (acc1.y + b1.y) * p1.y
                 + (acc1.z + b1.z) * p1.z + (acc1.w + b1.w) * p1.w;
        }
#pragma unroll
        for (int d = 8; d >= 1; d >>= 1) part += __shfl_xor(part, d, 64);
        if (lane == 0) logits[v] = part + pb[0];
    } else {
        if (lane < 16) {
            float4 b0 = *reinterpret_cast<const float4*>(&bias[f0]);
            float4 b1 = *reinterpret_cast<const float4*>(&bias[64 + f0]);
            acc0.x += b0.x; acc0.y += b0.y; acc0.z += b0.z; acc0.w += b0.w;
            acc1.x += b1.x; acc1.y += b1.y; acc1.z += b1.z; acc1.w += b1.w;
            *reinterpret_cast<float4*>(&xout[(size_t)v * 128 + f0])      = acc0;
            *reinterpret_cast<float4*>(&xout[(size_t)v * 128 + 64 + f0]) = acc1;
        }
    }
}

// ---------------------------------------------------------------------------
extern "C" void kernel_launch(void* const* d_in, const int* in_sizes, int n_in,
                              void* d_out, int out_size, void* d_ws, size_t ws_size,
                              hipStream_t stream)
{
    const float* weights = (const float*)d_in[0];
    const float* lin_W   = (const float*)d_in[1];
    const float* lin_b   = (const float*)d_in[2];
    const float* fc_W    = (const float*)d_in[3];
    const float* attn_l  = (const float*)d_in[4];
    const float* attn_r  = (const float*)d_in[5];
    const float* conv_b  = (const float*)d_in[6];
    const float* pred_W  = (const float*)d_in[7];
    const float* pred_b  = (const float*)d_in[8];
    const int*   src     = (const int*)d_in[9];
    const int*   dst     = (const int*)d_in[10];

    const int N = in_sizes[0];
    const int E = in_sizes[9];
    const int NB = (N + SCAN_TILE - 1) / SCAN_TILE;

    // workspace layout (16B-aligned float4 sections first)
    float* x   = (float*)d_ws;                   // N*128
    float* h   = x + (size_t)N * 128;            // N*128
    float* el  = h + (size_t)N * 128;            // N*4
    float* er  = el + (size_t)N * 4;             // N*4
    float* c1  = er + (size_t)N * 4;             // 128
    float* c2  = c1 + 128;                       // 128
    float* prm = c2 + 128;                       // 16
    int*   deg  = (int*)(prm + 16);              // N
    int*   rowp = deg + N;                       // N+1
    int*   cur  = rowp + (N + 1);                // N
    int*   col  = cur + N;                       // E+N
    int*   bsum = col + (E + N);                 // NB
    int*   bpre = bsum + NB;                     // NB

    // CSR build (fresh every call: ws is re-poisoned)
    deg_init_kernel<<<(N + 255) / 256, 256, 0, stream>>>(deg, N);
    deg_count_kernel<<<(E + 255) / 256, 256, 0, stream>>>(dst, deg, E);
    scanA_kernel<<<NB, 256, 0, stream>>>(deg, bsum, N);
    scanB_kernel<<<1, 1024, 0, stream>>>(bsum, bpre, rowp, NB, N);
    scanC_kernel<<<NB, 256, 0, stream>>>(deg, bpre, rowp, cur, N);
    scatter_kernel<<<(E + N + 255) / 256, 256, 0, stream>>>(src, dst, cur, col, E, N);

    // Layer 0 via rank-1 identity
    rank1_prep_kernel<<<1, 128, 0, stream>>>(lin_W, lin_b, fc_W, attn_l, attn_r,
                                             c1, c2, prm);
    rank1_apply_kernel<<<((size_t)N * 32 + 255) / 256, 256, 0, stream>>>(
        weights, c1, c2, prm, h, el, er, N);
    agg_fused_kernel<<<(N + 3) / 4, 256, 0, stream>>>(
        h, el, er, rowp, col, conv_b, x, pred_W, pred_b, (float*)d_out, N, 0);

    // Layers 1, 2
    for (int l = 1; l < 3; ++l) {
        gemm_kernel<<<(N + 127) / 128, 256, 0, stream>>>(
            x, fc_W + (size_t)l * 128 * 128, h, N);
        elr_kernel<<<(N + 3) / 4, 256, 0, stream>>>(
            h, attn_l + l * 128, attn_r + l * 128, el, er, N);
        agg_fused_kernel<<<(N + 3) / 4, 256, 0, stream>>>(
            h, el, er, rowp, col, conv_b + l * 128, x, pred_W, pred_b,
            (float*)d_out, N, l == 2 ? 1 : 0);
    }
}

// Round 5
// 582.172 us; speedup vs baseline: 1.8448x; 1.0702x over previous
//
#include <hip/hip_runtime.h>
#include <hip/hip_bf16.h>
#include <math.h>

// Problem constants: N=100000, E=600000, D=128, H=4, F=32, L=3

__device__ __forceinline__ float leaky02(float x) {
    return x >= 0.f ? x : 0.2f * x;
}

// ---------------------------------------------------------------------------
// CSR build
__global__ __launch_bounds__(256) void deg_init_kernel(int* __restrict__ deg, int N)
{
    int i = blockIdx.x * 256 + threadIdx.x;
    if (i < N) deg[i] = 1;  // self loop
}

__global__ __launch_bounds__(256) void deg_count_kernel(
    const int* __restrict__ dst, int* __restrict__ deg, int E)
{
    int i = blockIdx.x * 256 + threadIdx.x;
    if (i < E) atomicAdd(&deg[dst[i]], 1);
}

#define SCAN_TILE 1024

__global__ __launch_bounds__(256) void scanA_kernel(
    const int* __restrict__ deg, int* __restrict__ bsum, int N)
{
    __shared__ int ws[4];
    int b = blockIdx.x, t = threadIdx.x;
    int base = b * SCAN_TILE + t * 4;
    int s = 0;
#pragma unroll
    for (int k = 0; k < 4; ++k) {
        int i = base + k;
        if (i < N) s += deg[i];
    }
#pragma unroll
    for (int m = 32; m >= 1; m >>= 1) s += __shfl_xor(s, m, 64);
    if ((t & 63) == 0) ws[t >> 6] = s;
    __syncthreads();
    if (t == 0) bsum[b] = ws[0] + ws[1] + ws[2] + ws[3];
}

__global__ __launch_bounds__(1024) void scanB_kernel(
    int* __restrict__ bsum, int* __restrict__ bpre, int* __restrict__ rowp,
    int NB, int N)
{
    __shared__ int sh[1024];
    int t = threadIdx.x;
    int v = (t < NB) ? bsum[t] : 0;
    sh[t] = v;
    __syncthreads();
    for (int off = 1; off < 1024; off <<= 1) {
        int u = (t >= off) ? sh[t - off] : 0;
        __syncthreads();
        sh[t] += u;
        __syncthreads();
    }
    if (t < NB) bpre[t] = sh[t] - v;          // exclusive prefix
    if (t == 1023) rowp[N] = sh[1023];        // total
}

__global__ __launch_bounds__(256) void scanC_kernel(
    const int* __restrict__ deg, const int* __restrict__ bpre,
    int* __restrict__ rowp, int* __restrict__ cur, int N)
{
    __shared__ int sh[256];
    int b = blockIdx.x, t = threadIdx.x;
    int base = b * SCAN_TILE + t * 4;
    int v[4];
#pragma unroll
    for (int k = 0; k < 4; ++k) {
        int i = base + k;
        v[k] = (i < N) ? deg[i] : 0;
    }
    int tsum = v[0] + v[1] + v[2] + v[3];
    sh[t] = tsum;
    __syncthreads();
    for (int off = 1; off < 256; off <<= 1) {
        int u = (t >= off) ? sh[t - off] : 0;
        __syncthreads();
        sh[t] += u;
        __syncthreads();
    }
    int pre = bpre[b] + sh[t] - tsum;
#pragma unroll
    for (int k = 0; k < 4; ++k) {
        int i = base + k;
        if (i < N) { rowp[i] = pre; cur[i] = pre; }
        pre += v[k];
    }
}

__global__ __launch_bounds__(256) void scatter_kernel(
    const int* __restrict__ src, const int* __restrict__ dst,
    int* __restrict__ cur, int* __restrict__ col, int E, int N)
{
    int i = blockIdx.x * 256 + threadIdx.x;
    if (i < E) {
        int p = atomicAdd(&cur[dst[i]], 1);
        col[p] = src[i];
    } else if (i < E + N) {
        int v = i - E;
        int p = atomicAdd(&cur[v], 1);
        col[p] = v;  // self loop
    }
}

// ---------------------------------------------------------------------------
// Layer-0 rank-1 precompute
__global__ __launch_bounds__(128) void rank1_prep_kernel(
    const float* __restrict__ lW, const float* __restrict__ lb,
    const float* __restrict__ W0, const float* __restrict__ al,
    const float* __restrict__ ar, float* __restrict__ c1,
    float* __restrict__ c2, float* __restrict__ prm)
{
    int j = threadIdx.x;
    float s1 = 0.f, s2 = 0.f;
    for (int d = 0; d < 128; ++d) {
        float wv = W0[j * 128 + d];
        s1 += lW[d] * wv;
        s2 += lb[d] * wv;
    }
    c1[j] = s1; c2[j] = s2;
    __shared__ float sh1[128], sh2[128], sh3[128], sh4[128];
    sh1[j] = s1 * al[j]; sh2[j] = s2 * al[j];
    sh3[j] = s1 * ar[j]; sh4[j] = s2 * ar[j];
    __syncthreads();
    if (j < 4) {
        float p = 0.f, q = 0.f, r = 0.f, s = 0.f;
        for (int f = 0; f < 32; ++f) {
            p += sh1[j * 32 + f]; q += sh2[j * 32 + f];
            r += sh3[j * 32 + f]; s += sh4[j * 32 + f];
        }
        prm[j] = p; prm[4 + j] = q; prm[8 + j] = r; prm[12 + j] = s;
    }
}

// h0[n,j] = w[n]*c1[j] + c2[j]; el0[n,h] = w[n]*pl[h]+ql[h]; er0 likewise.
__global__ __launch_bounds__(256) void rank1_apply_kernel(
    const float* __restrict__ w, const float* __restrict__ c1,
    const float* __restrict__ c2, const float* __restrict__ prm,
    float* __restrict__ h, float* __restrict__ el, float* __restrict__ er, int N)
{
    int i = blockIdx.x * 256 + threadIdx.x;
    int n = i >> 5, k = i & 31;
    if (n >= N) return;
    float wn = w[n];
    float4 a = *reinterpret_cast<const float4*>(&c1[k * 4]);
    float4 b = *reinterpret_cast<const float4*>(&c2[k * 4]);
    float4 o = make_float4(wn * a.x + b.x, wn * a.y + b.y,
                           wn * a.z + b.z, wn * a.w + b.w);
    *reinterpret_cast<float4*>(&h[(size_t)n * 128 + k * 4]) = o;
    if (k == 0) {
        float4 pl = *reinterpret_cast<const float4*>(&prm[0]);
        float4 ql = *reinterpret_cast<const float4*>(&prm[4]);
        float4 pr = *reinterpret_cast<const float4*>(&prm[8]);
        float4 qr = *reinterpret_cast<const float4*>(&prm[12]);
        float4 e1 = make_float4(wn * pl.x + ql.x, wn * pl.y + ql.y,
                                wn * pl.z + ql.z, wn * pl.w + ql.w);
        float4 e2 = make_float4(wn * pr.x + qr.x, wn * pr.y + qr.y,
                                wn * pr.z + qr.z, wn * pr.w + qr.w);
        *reinterpret_cast<float4*>(&el[(size_t)n * 4]) = e1;
        *reinterpret_cast<float4*>(&er[(size_t)n * 4]) = e2;
    }
}

// ---------------------------------------------------------------------------
// GEMM (layers 1,2): h[n,j] = sum_d leaky0.01(x[n,d]) * W[j,d]
__global__ __launch_bounds__(256) void gemm_kernel(
    const float* __restrict__ x, const float* __restrict__ W,
    float* __restrict__ h, int N)
{
    __shared__ float xs[32][132];
    __shared__ float wsh[32][132];
    const int tid = threadIdx.x;
    const int m0 = blockIdx.x * 128;
    const int tx = tid & 15;
    const int ty = tid >> 4;
    const int lr = tid >> 3;
    const int lc = (tid & 7) * 4;

    float acc[8][8];
#pragma unroll
    for (int r = 0; r < 8; ++r)
#pragma unroll
        for (int c = 0; c < 8; ++c) acc[r][c] = 0.f;

    for (int k0 = 0; k0 < 128; k0 += 32) {
#pragma unroll
        for (int p = 0; p < 4; ++p) {
            int row = m0 + lr + p * 32;
            float4 v = make_float4(0.f, 0.f, 0.f, 0.f);
            if (row < N) v = *reinterpret_cast<const float4*>(&x[(size_t)row * 128 + k0 + lc]);
            v.x = v.x >= 0.f ? v.x : 0.01f * v.x;
            v.y = v.y >= 0.f ? v.y : 0.01f * v.y;
            v.z = v.z >= 0.f ? v.z : 0.01f * v.z;
            v.w = v.w >= 0.f ? v.w : 0.01f * v.w;
            xs[lc + 0][lr + p * 32] = v.x;
            xs[lc + 1][lr + p * 32] = v.y;
            xs[lc + 2][lr + p * 32] = v.z;
            xs[lc + 3][lr + p * 32] = v.w;
        }
#pragma unroll
        for (int p = 0; p < 4; ++p) {
            int j = lr + p * 32;
            float4 v = *reinterpret_cast<const float4*>(&W[(size_t)j * 128 + k0 + lc]);
            wsh[lc + 0][j] = v.x;
            wsh[lc + 1][j] = v.y;
            wsh[lc + 2][j] = v.z;
            wsh[lc + 3][j] = v.w;
        }
        __syncthreads();

#pragma unroll
        for (int d = 0; d < 32; ++d) {
            const float4 a0 = *reinterpret_cast<const float4*>(&xs[d][ty * 8]);
            const float4 a1 = *reinterpret_cast<const float4*>(&xs[d][ty * 8 + 4]);
            const float4 b0 = *reinterpret_cast<const float4*>(&wsh[d][tx * 4]);
            const float4 b1 = *reinterpret_cast<const float4*>(&wsh[d][64 + tx * 4]);
            const float av[8] = {a0.x, a0.y, a0.z, a0.w, a1.x, a1.y, a1.z, a1.w};
            const float bv[8] = {b0.x, b0.y, b0.z, b0.w, b1.x, b1.y, b1.z, b1.w};
#pragma unroll
            for (int r = 0; r < 8; ++r)
#pragma unroll
                for (int c = 0; c < 8; ++c) acc[r][c] += av[r] * bv[c];
        }
        __syncthreads();
    }

#pragma unroll
    for (int r = 0; r < 8; ++r) {
        int row = m0 + ty * 8 + r;
        if (row < N) {
            float4 lo = make_float4(acc[r][0], acc[r][1], acc[r][2], acc[r][3]);
            float4 hi = make_float4(acc[r][4], acc[r][5], acc[r][6], acc[r][7]);
            *reinterpret_cast<float4*>(&h[(size_t)row * 128 + tx * 4])      = lo;
            *reinterpret_cast<float4*>(&h[(size_t)row * 128 + 64 + tx * 4]) = hi;
        }
    }
}

// ---------------------------------------------------------------------------
// el/er reduction (layers 1,2). One wave per node.
__global__ __launch_bounds__(256) void elr_kernel(
    const float* __restrict__ h, const float* __restrict__ al,
    const float* __restrict__ ar, float* __restrict__ el,
    float* __restrict__ er, int N)
{
    int node = blockIdx.x * 4 + (threadIdx.x >> 6);
    int lane = threadIdx.x & 63;
    if (node >= N) return;
    float v0 = h[(size_t)node * 128 + lane];
    float v1 = h[(size_t)node * 128 + 64 + lane];
    float sl0 = v0 * al[lane];
    float sl1 = v1 * al[64 + lane];
    float sr0 = v0 * ar[lane];
    float sr1 = v1 * ar[64 + lane];
#pragma unroll
    for (int m = 16; m >= 1; m >>= 1) {
        sl0 += __shfl_xor(sl0, m, 64);
        sl1 += __shfl_xor(sl1, m, 64);
        sr0 += __shfl_xor(sr0, m, 64);
        sr1 += __shfl_xor(sr1, m, 64);
    }
    if ((lane & 31) == 0) {
        int hb = lane >> 5;
        el[node * 4 + hb]     = sl0;
        el[node * 4 + hb + 2] = sl1;
        er[node * 4 + hb]     = sr0;
        er[node * 4 + hb + 2] = sr1;
    }
}

// ---------------------------------------------------------------------------
// Fused softmax-stats + gather + (optional) prediction epilogue.
// One wave per node.
// Phase A (head-quartered): lane = head*16 + slot; per-lane serial online
//   (m,s) over edge slots, then 4-step butterfly merge over the 16-lane
//   quarter. 8 shuffles total, no per-head reduction loops.
// Phase B: quarter-wave per edge (4 edges in flight); col/el loaded DIRECTLY
//   per lane (no shuffle broadcast) so loop iterations are independent and
//   loads pipeline. Stats broadcast once before the loop.
__global__ __launch_bounds__(256) void agg_fused_kernel(
    const float* __restrict__ h, const float* __restrict__ el,
    const float* __restrict__ er, const int* __restrict__ rowp,
    const int* __restrict__ col, const float* __restrict__ bias,
    float* __restrict__ xout, const float* __restrict__ pW,
    const float* __restrict__ pb, float* __restrict__ logits,
    int N, int last)
{
    int v = blockIdx.x * 4 + (threadIdx.x >> 6);
    int lane = threadIdx.x & 63;
    if (v >= N) return;
    const int r0 = rowp[v], r1 = rowp[v + 1];
    const int deg = r1 - r0;

    // ---- Phase A: per-head online softmax stats
    const int qh  = lane >> 4;      // head handled by this quarter
    const int j16 = lane & 15;      // edge slot within quarter
    const float erq = er[(size_t)v * 4 + qh];

    float m_l = -INFINITY, s_l = 0.f;
    for (int jj = j16; jj < deg; jj += 16) {
        int u = col[r0 + jj];
        float e = leaky02(el[(size_t)u * 4 + qh] + erq);
        if (e > m_l) { s_l = s_l * __expf(m_l - e) + 1.f; m_l = e; }
        else         { s_l += __expf(e - m_l); }
    }
    // butterfly merge over the 16-lane quarter (online-combine m,s)
#pragma unroll
    for (int d = 1; d <= 8; d <<= 1) {
        float m2 = __shfl_xor(m_l, d, 64);
        float s2 = __shfl_xor(s_l, d, 64);
        float nm = fmaxf(m_l, m2);
        s_l = (s_l > 0.f ? s_l * __expf(m_l - nm) : 0.f)
            + (s2  > 0.f ? s2  * __expf(m2  - nm) : 0.f);
        m_l = nm;
    }
    const float is_l = 1.f / s_l;

    // ---- Phase B: gather, 4 edges in flight (quarter-wave per edge)
    const int q = lane >> 4, l16 = lane & 15, f0 = l16 * 4, hA = l16 >> 3;
    // broadcast stats for this lane's two head slots (quarter hA / hA+2)
    const float mA  = __shfl(m_l,  hA * 16, 64);
    const float isA = __shfl(is_l, hA * 16, 64);
    const float mB  = __shfl(m_l,  (hA + 2) * 16, 64);
    const float isB = __shfl(is_l, (hA + 2) * 16, 64);
    const float erA = er[(size_t)v * 4 + hA];
    const float erB = er[(size_t)v * 4 + 2 + hA];

    float4 acc0 = make_float4(0.f, 0.f, 0.f, 0.f);
    float4 acc1 = make_float4(0.f, 0.f, 0.f, 0.f);

    for (int j = r0 + q; j < r1; j += 4) {
        int u = col[j];
        float eA = leaky02(el[(size_t)u * 4 + hA] + erA);
        float eB = leaky02(el[(size_t)u * 4 + 2 + hA] + erB);
        float aA = __expf(eA - mA) * isA;
        float aB = __expf(eB - mB) * isB;
        const float4 v0 = *reinterpret_cast<const float4*>(&h[(size_t)u * 128 + f0]);
        const float4 v1 = *reinterpret_cast<const float4*>(&h[(size_t)u * 128 + 64 + f0]);
        acc0.x += aA * v0.x; acc0.y += aA * v0.y;
        acc0.z += aA * v0.z; acc0.w += aA * v0.w;
        acc1.x += aB * v1.x; acc1.y += aB * v1.y;
        acc1.z += aB * v1.z; acc1.w += aB * v1.w;
    }

    // combine quarter-wave partials (lanes l, l^16, l^32, l^48)
#pragma unroll
    for (int d = 16; d <= 32; d <<= 1) {
        acc0.x += __shfl_xor(acc0.x, d, 64);
        acc0.y += __shfl_xor(acc0.y, d, 64);
        acc0.z += __shfl_xor(acc0.z, d, 64);
        acc0.w += __shfl_xor(acc0.w, d, 64);
        acc1.x += __shfl_xor(acc1.x, d, 64);
        acc1.y += __shfl_xor(acc1.y, d, 64);
        acc1.z += __shfl_xor(acc1.z, d, 64);
        acc1.w += __shfl_xor(acc1.w, d, 64);
    }

    if (last) {
        float part = 0.f;
        if (lane < 16) {
            float4 b0 = *reinterpret_cast<const float4*>(&bias[f0]);
            float4 b1 = *reinterpret_cast<const float4*>(&bias[64 + f0]);
            float4 p0 = *reinterpret_cast<const float4*>(&pW[f0]);
            float4 p1 = *reinterpret_cast<const float4*>(&pW[64 + f0]);
            part = (acc0.x + b0.x) * p0.x + (acc0.y + b0.y) * p0.y
                 + (acc0.z + b0.z) * p0.z + (acc0.w + b0.w) * p0.w
                 + (acc1.x + b1.x) * p1.x + (acc1.y + b1.y) * p1.y
                 + (acc1.z + b1.z) * p1.z + (acc1.w + b1.w) * p1.w;
        }
#pragma unroll
        for (int d = 8; d >= 1; d >>= 1) part += __shfl_xor(part, d, 64);
        if (lane == 0) logits[v] = part + pb[0];
    } else {
        if (lane < 16) {
            float4 b0 = *reinterpret_cast<const float4*>(&bias[f0]);
            float4 b1 = *reinterpret_cast<const float4*>(&bias[64 + f0]);
            acc0.x += b0.x; acc0.y += b0.y; acc0.z += b0.z; acc0.w += b0.w;
            acc1.x += b1.x; acc1.y += b1.y; acc1.z += b1.z; acc1.w += b1.w;
            *reinterpret_cast<float4*>(&xout[(size_t)v * 128 + f0])      = acc0;
            *reinterpret_cast<float4*>(&xout[(size_t)v * 128 + 64 + f0]) = acc1;
        }
    }
}

// ---------------------------------------------------------------------------
extern "C" void kernel_launch(void* const* d_in, const int* in_sizes, int n_in,
                              void* d_out, int out_size, void* d_ws, size_t ws_size,
                              hipStream_t stream)
{
    const float* weights = (const float*)d_in[0];
    const float* lin_W   = (const float*)d_in[1];
    const float* lin_b   = (const float*)d_in[2];
    const float* fc_W    = (const float*)d_in[3];
    const float* attn_l  = (const float*)d_in[4];
    const float* attn_r  = (const float*)d_in[5];
    const float* conv_b  = (const float*)d_in[6];
    const float* pred_W  = (const float*)d_in[7];
    const float* pred_b  = (const float*)d_in[8];
    const int*   src     = (const int*)d_in[9];
    const int*   dst     = (const int*)d_in[10];

    const int N = in_sizes[0];
    const int E = in_sizes[9];
    const int NB = (N + SCAN_TILE - 1) / SCAN_TILE;

    // workspace layout (16B-aligned float4 sections first)
    float* x   = (float*)d_ws;                   // N*128
    float* h   = x + (size_t)N * 128;            // N*128
    float* el  = h + (size_t)N * 128;            // N*4
    float* er  = el + (size_t)N * 4;             // N*4
    float* c1  = er + (size_t)N * 4;             // 128
    float* c2  = c1 + 128;                       // 128
    float* prm = c2 + 128;                       // 16
    int*   deg  = (int*)(prm + 16);              // N
    int*   rowp = deg + N;                       // N+1
    int*   cur  = rowp + (N + 1);                // N
    int*   col  = cur + N;                       // E+N
    int*   bsum = col + (E + N);                 // NB
    int*   bpre = bsum + NB;                     // NB

    // CSR build (fresh every call: ws is re-poisoned)
    deg_init_kernel<<<(N + 255) / 256, 256, 0, stream>>>(deg, N);
    deg_count_kernel<<<(E + 255) / 256, 256, 0, stream>>>(dst, deg, E);
    scanA_kernel<<<NB, 256, 0, stream>>>(deg, bsum, N);
    scanB_kernel<<<1, 1024, 0, stream>>>(bsum, bpre, rowp, NB, N);
    scanC_kernel<<<NB, 256, 0, stream>>>(deg, bpre, rowp, cur, N);
    scatter_kernel<<<(E + N + 255) / 256, 256, 0, stream>>>(src, dst, cur, col, E, N);

    // Layer 0 via rank-1 identity
    rank1_prep_kernel<<<1, 128, 0, stream>>>(lin_W, lin_b, fc_W, attn_l, attn_r,
                                             c1, c2, prm);
    rank1_apply_kernel<<<((size_t)N * 32 + 255) / 256, 256, 0, stream>>>(
        weights, c1, c2, prm, h, el, er, N);
    agg_fused_kernel<<<(N + 3) / 4, 256, 0, stream>>>(
        h, el, er, rowp, col, conv_b, x, pred_W, pred_b, (float*)d_out, N, 0);

    // Layers 1, 2
    for (int l = 1; l < 3; ++l) {
        gemm_kernel<<<(N + 127) / 128, 256, 0, stream>>>(
            x, fc_W + (size_t)l * 128 * 128, h, N);
        elr_kernel<<<(N + 3) / 4, 256, 0, stream>>>(
            h, attn_l + l * 128, attn_r + l * 128, el, er, N);
        agg_fused_kernel<<<(N + 3) / 4, 256, 0, stream>>>(
            h, el, er, rowp, col, conv_b + l * 128, x, pred_W, pred_b,
            (float*)d_out, N, l == 2 ? 1 : 0);
    }
}